// Round 1
// baseline (352.545 us; speedup 1.0000x reference)
//
#include <hip/hip_runtime.h>
#include <math.h>

constexpr int B  = 128;
constexpr int R  = 4096;
constexpr int IC = 8;
constexpr int C  = 10;
constexpr int O  = 16;

constexpr int RT = 16;           // r's per block (4 waves x 4 r-slots)
constexpr int BT = 16;           // b's per block
constexpr int NRBLK = R / RT;    // 256
constexpr int CO = C * O;        // 160

// Pass kernel: each thread owns (r, o), holds W[r, :, o, :] in registers,
// loops over BT batches. IT = routing iteration (0,1,2).
template<int IT>
__global__ __launch_bounds__(256, 2)
void pass_kernel(const float* __restrict__ x, const float* __restrict__ W,
                 const float* __restrict__ v_prev, float* __restrict__ b_buf,
                 float* __restrict__ s_part)
{
    const int tid  = threadIdx.x;
    const int wave = tid >> 6;
    const int lane = tid & 63;
    const int o    = lane & 15;      // capsule-vector element
    const int rs   = lane >> 4;      // r slot within wave
    const int rblk = blockIdx.x;
    const int r    = rblk * RT + wave * 4 + rs;
    const int b0   = blockIdx.y * BT;

    // ---- load W[r, c, o, 0..7] into registers (80 floats) ----
    float wreg[C][IC];
    {
        const float* wp = W + ((size_t)r * C * O + o) * IC;
        #pragma unroll
        for (int c = 0; c < C; ++c) {
            const float4* p = reinterpret_cast<const float4*>(wp + (size_t)c * O * IC);
            float4 w0 = p[0], w1 = p[1];
            wreg[c][0] = w0.x; wreg[c][1] = w0.y; wreg[c][2] = w0.z; wreg[c][3] = w0.w;
            wreg[c][4] = w1.x; wreg[c][5] = w1.y; wreg[c][6] = w1.z; wreg[c][7] = w1.w;
        }
    }

    __shared__ float sred[4][CO];

    for (int b = b0; b < b0 + BT; ++b) {
        // ---- x[b, r, 0..7] ----
        const float4* xp = reinterpret_cast<const float4*>(x + ((size_t)b * R + r) * IC);
        float4 x0 = xp[0], x1 = xp[1];
        float xv[IC] = {x0.x, x0.y, x0.z, x0.w, x1.x, x1.y, x1.z, x1.w};

        // ---- u_hat[c] for this (r, o) ----
        float uh[C];
        #pragma unroll
        for (int c = 0; c < C; ++c) {
            float acc = 0.f;
            #pragma unroll
            for (int i = 0; i < IC; ++i) acc = fmaf(wreg[c][i], xv[i], acc);
            uh[c] = acc;
        }

        // ---- routing weights ----
        float wgt[C];
        if constexpr (IT == 0) {
            #pragma unroll
            for (int c = 0; c < C; ++c) wgt[c] = 0.1f;   // softmax of zeros
        } else {
            // agreement a[c] = sum_o uh[c,o] * v_prev[b,c,o]
            float a[C];
            #pragma unroll
            for (int c = 0; c < C; ++c)
                a[c] = uh[c] * v_prev[((size_t)b * C + c) * O + o];
            #pragma unroll
            for (int m = 1; m < 16; m <<= 1) {
                #pragma unroll
                for (int c = 0; c < C; ++c)
                    a[c] += __shfl_xor(a[c], m, 16);
            }
            // logits b_ij
            float bn[C];
            if constexpr (IT == 2) {
                const float* bp = b_buf + ((size_t)b * R + r) * C;
                #pragma unroll
                for (int c = 0; c < C; ++c) bn[c] = bp[c] + a[c];
            } else {
                #pragma unroll
                for (int c = 0; c < C; ++c) bn[c] = a[c];
                if (o == 0) {   // persist for next iteration
                    float* bp = b_buf + ((size_t)b * R + r) * C;
                    #pragma unroll
                    for (int c = 0; c < C; ++c) bp[c] = bn[c];
                }
            }
            // softmax over c, fully in-register (redundant across o-lanes)
            float mx = bn[0];
            #pragma unroll
            for (int c = 1; c < C; ++c) mx = fmaxf(mx, bn[c]);
            float sum = 0.f;
            #pragma unroll
            for (int c = 0; c < C; ++c) { wgt[c] = __expf(bn[c] - mx); sum += wgt[c]; }
            float inv = 1.f / sum;
            #pragma unroll
            for (int c = 0; c < C; ++c) wgt[c] *= inv;
        }

        // ---- weighted contribution, reduce over the 4 r-slots in wave ----
        float t[C];
        #pragma unroll
        for (int c = 0; c < C; ++c) t[c] = wgt[c] * uh[c];
        #pragma unroll
        for (int c = 0; c < C; ++c) {
            t[c] += __shfl_xor(t[c], 16, 64);
            t[c] += __shfl_xor(t[c], 32, 64);
        }

        // ---- cross-wave reduce in LDS, emit per-rblock partial ----
        __syncthreads();   // protect sred from previous iteration's readers
        if (rs == 0) {
            #pragma unroll
            for (int c = 0; c < C; ++c) sred[wave][c * O + o] = t[c];
        }
        __syncthreads();
        if (tid < CO) {
            float s4 = sred[0][tid] + sred[1][tid] + sred[2][tid] + sred[3][tid];
            s_part[((size_t)rblk * B + b) * CO + tid] = s4;
        }
    }
}

// Sum partials over rblocks, add bias, squash, write v (or final output).
__global__ __launch_bounds__(192)
void reduce_squash(const float* __restrict__ s_part, const float* __restrict__ bias,
                   float* __restrict__ v_out)
{
    const int b = blockIdx.x;
    const int t = threadIdx.x;   // 0..191, first 160 active
    __shared__ float sv[CO];
    float acc = 0.f;
    if (t < CO) {
        for (int blk = 0; blk < NRBLK; ++blk)
            acc += s_part[((size_t)blk * B + b) * CO + t];
        acc += bias[t];
        sv[t] = acc;
    }
    __syncthreads();
    if (t < CO) {
        const int c = t >> 4;
        float n = 0.f;
        #pragma unroll
        for (int oo = 0; oo < O; ++oo) { float z = sv[c * O + oo]; n += z * z; }
        // squash: s * sqrt(n) / (1 + n)
        v_out[(size_t)b * CO + t] = acc * sqrtf(n) / (1.f + n);
    }
}

extern "C" void kernel_launch(void* const* d_in, const int* in_sizes, int n_in,
                              void* d_out, int out_size, void* d_ws, size_t ws_size,
                              hipStream_t stream)
{
    const float* x    = (const float*)d_in[0];
    const float* W    = (const float*)d_in[1];
    const float* bias = (const float*)d_in[2];
    float* out = (float*)d_out;

    float* ws     = (float*)d_ws;
    float* s_part = ws;                                    // NRBLK*B*CO floats (21 MB)
    float* b_buf  = s_part + (size_t)NRBLK * B * CO;       // B*R*C floats (21 MB)
    float* v_buf  = b_buf + (size_t)B * R * C;             // B*CO floats

    dim3 grid(NRBLK, B / BT);
    dim3 blk(256);

    pass_kernel<0><<<grid, blk, 0, stream>>>(x, W, nullptr, b_buf, s_part);
    reduce_squash<<<B, 192, 0, stream>>>(s_part, bias, v_buf);
    pass_kernel<1><<<grid, blk, 0, stream>>>(x, W, v_buf, b_buf, s_part);
    reduce_squash<<<B, 192, 0, stream>>>(s_part, bias, v_buf);
    pass_kernel<2><<<grid, blk, 0, stream>>>(x, W, v_buf, b_buf, s_part);
    reduce_squash<<<B, 192, 0, stream>>>(s_part, bias, out);
}

// Round 2
// 289.022 us; speedup vs baseline: 1.2198x; 1.2198x over previous
//
#include <hip/hip_runtime.h>
#include <math.h>

constexpr int B  = 128;
constexpr int R  = 4096;
constexpr int IC = 8;
constexpr int C  = 10;
constexpr int O  = 16;

constexpr int RT = 16;           // r's per block (4 waves x 4 r-slots)
constexpr int BT = 16;           // b's per block
constexpr int NRBLK = R / RT;    // 256
constexpr int CO = C * O;        // 160

// Pass kernel: thread = (r, o). Holds W[r,:,o,:] pinned in 80 VGPRs, loops
// over BT batches with NO in-loop barriers. Per-wave partials staged in LDS
// for all BT b's; single barrier + coalesced epilogue.
// IT = routing iteration. Logits for iter k are uh . vsum (vsum = v0+..+v_{k-1})
// because agreement is linear in v — no b_ij buffer needed.
template<int IT>
__global__ __launch_bounds__(256, 3)
void pass_kernel(const float* __restrict__ x, const float* __restrict__ W,
                 const float* __restrict__ vsum, float* __restrict__ s_part)
{
    const int tid  = threadIdx.x;
    const int w    = tid >> 6;
    const int lane = tid & 63;
    const int o    = lane & 15;      // capsule-vector element
    const int rs   = lane >> 4;      // r slot within wave
    const int rblk = blockIdx.x;
    const int r    = rblk * RT + w * 4 + rs;
    const int b0   = blockIdx.y * BT;

    __shared__ float vL[BT][CO];          // 10 KB: vsum for this block's b's
    __shared__ float stage[4][BT][CO];    // 40 KB: per-wave partials, all b's

    if constexpr (IT >= 1) {
        for (int k = tid; k < BT * CO; k += 256)
            (&vL[0][0])[k] = vsum[(size_t)b0 * CO + k];
    }

    // ---- load W[r, c, o, 0..7] into registers (80 floats), pinned ----
    float wreg[C][IC];
    {
        const float* wp = W + ((size_t)r * C * O + o) * IC;
        #pragma unroll
        for (int c = 0; c < C; ++c) {
            const float4* p = reinterpret_cast<const float4*>(wp + (size_t)c * O * IC);
            float4 w0 = p[0], w1 = p[1];
            wreg[c][0] = w0.x; wreg[c][1] = w0.y; wreg[c][2] = w0.z; wreg[c][3] = w0.w;
            wreg[c][4] = w1.x; wreg[c][5] = w1.y; wreg[c][6] = w1.z; wreg[c][7] = w1.w;
        }
    }
    #pragma unroll
    for (int c = 0; c < C; ++c)
        #pragma unroll
        for (int i = 0; i < IC; ++i)
            asm volatile("" : "+v"(wreg[c][i]));   // forbid remat/reload from W

    if constexpr (IT >= 1) __syncthreads();        // vL ready

    for (int bb = 0; bb < BT; ++bb) {
        const int b = b0 + bb;

        // ---- x[b, r, 0..7] ----
        const float4* xp = reinterpret_cast<const float4*>(x + ((size_t)b * R + r) * IC);
        float4 x0 = xp[0], x1 = xp[1];
        float xv[IC] = {x0.x, x0.y, x0.z, x0.w, x1.x, x1.y, x1.z, x1.w};

        // ---- u_hat[c] for this (r, o) ----
        float uh[C];
        #pragma unroll
        for (int c = 0; c < C; ++c) {
            float acc = 0.f;
            #pragma unroll
            for (int i = 0; i < IC; ++i) acc = fmaf(wreg[c][i], xv[i], acc);
            uh[c] = acc;
        }

        // ---- t[c] = routing_weight[c] * uh[c] ----
        float t[C];
        if constexpr (IT == 0) {
            #pragma unroll
            for (int c = 0; c < C; ++c) t[c] = 0.1f * uh[c];   // softmax of zeros
        } else {
            // logits b_ij = sum_o uh[c,o] * vsum[b,c,o]
            float a[C];
            #pragma unroll
            for (int c = 0; c < C; ++c) a[c] = uh[c] * vL[bb][c * O + o];
            #pragma unroll
            for (int m = 1; m < 16; m <<= 1) {
                #pragma unroll
                for (int c = 0; c < C; ++c) a[c] += __shfl_xor(a[c], m, 16);
            }
            // softmax over c, in-register (redundant across the 16 o-lanes)
            float mx = a[0];
            #pragma unroll
            for (int c = 1; c < C; ++c) mx = fmaxf(mx, a[c]);
            float sum = 0.f;
            #pragma unroll
            for (int c = 0; c < C; ++c) { a[c] = __expf(a[c] - mx); sum += a[c]; }
            float inv = 1.f / sum;
            #pragma unroll
            for (int c = 0; c < C; ++c) t[c] = (a[c] * inv) * uh[c];
        }

        // ---- reduce over the 4 r-slots in wave ----
        #pragma unroll
        for (int c = 0; c < C; ++c) {
            t[c] += __shfl_xor(t[c], 16, 64);
            t[c] += __shfl_xor(t[c], 32, 64);
        }

        // ---- stash per-wave partial (no barrier) ----
        if (rs == 0) {
            #pragma unroll
            for (int c = 0; c < C; ++c) stage[w][bb][c * O + o] = t[c];
        }
    }

    __syncthreads();

    // ---- epilogue: cross-wave sum, coalesced store ----
    if (tid < CO) {
        #pragma unroll 4
        for (int bb = 0; bb < BT; ++bb) {
            float s4 = stage[0][bb][tid] + stage[1][bb][tid]
                     + stage[2][bb][tid] + stage[3][bb][tid];
            s_part[((size_t)rblk * B + (b0 + bb)) * CO + tid] = s4;
        }
    }
}

// Sum partials over rblocks (4-way split), add bias, squash.
// Writes v (if v_out) and vsum_out = vin_sum + v (if vsum_out).
__global__ __launch_bounds__(640)
void reduce_squash(const float* __restrict__ s_part, const float* __restrict__ bias,
                   const float* __restrict__ vin_sum,
                   float* __restrict__ v_out, float* __restrict__ vsum_out)
{
    const int b = blockIdx.x;
    const int t = threadIdx.x;        // 640 threads: 4 quarters x 160
    __shared__ float part[4][CO];
    __shared__ float sv[CO];

    if (t < 4 * CO) {
        const int q  = t / CO;
        const int co = t % CO;
        float acc = 0.f;
        for (int blk = q * (NRBLK / 4); blk < (q + 1) * (NRBLK / 4); ++blk)
            acc += s_part[((size_t)blk * B + b) * CO + co];
        part[q][co] = acc;
    }
    __syncthreads();

    float s = 0.f;
    if (t < CO) {
        s = part[0][t] + part[1][t] + part[2][t] + part[3][t] + bias[t];
        sv[t] = s;
    }
    __syncthreads();

    if (t < CO) {
        const int c = t >> 4;
        float n = 0.f;
        #pragma unroll
        for (int oo = 0; oo < O; ++oo) { float z = sv[c * O + oo]; n += z * z; }
        float v = s * sqrtf(n) / (1.f + n);            // squash
        if (v_out)    v_out[(size_t)b * CO + t] = v;
        if (vsum_out) vsum_out[(size_t)b * CO + t] = (vin_sum ? vin_sum[(size_t)b * CO + t] : 0.f) + v;
    }
}

extern "C" void kernel_launch(void* const* d_in, const int* in_sizes, int n_in,
                              void* d_out, int out_size, void* d_ws, size_t ws_size,
                              hipStream_t stream)
{
    const float* x    = (const float*)d_in[0];
    const float* W    = (const float*)d_in[1];
    const float* bias = (const float*)d_in[2];
    float* out = (float*)d_out;

    float* ws     = (float*)d_ws;
    float* s_part = ws;                                    // NRBLK*B*CO floats (21 MB)
    float* vsumA  = s_part + (size_t)NRBLK * B * CO;       // B*CO floats
    float* vsumB  = vsumA + (size_t)B * CO;                // B*CO floats

    dim3 grid(NRBLK, B / BT);
    dim3 blk(256);

    // iter 0: c = 1/10 uniform
    pass_kernel<0><<<grid, blk, 0, stream>>>(x, W, nullptr, s_part);
    reduce_squash<<<B, 640, 0, stream>>>(s_part, bias, nullptr, nullptr, vsumA);   // vsumA = v0
    // iter 1: logits = uh . v0
    pass_kernel<1><<<grid, blk, 0, stream>>>(x, W, vsumA, s_part);
    reduce_squash<<<B, 640, 0, stream>>>(s_part, bias, vsumA, nullptr, vsumB);     // vsumB = v0+v1
    // iter 2: logits = uh . (v0+v1)
    pass_kernel<2><<<grid, blk, 0, stream>>>(x, W, vsumB, s_part);
    reduce_squash<<<B, 640, 0, stream>>>(s_part, bias, nullptr, out, nullptr);     // out = v2
}

// Round 3
// 276.189 us; speedup vs baseline: 1.2765x; 1.0465x over previous
//
#include <hip/hip_runtime.h>
#include <math.h>

constexpr int B  = 128;
constexpr int R  = 4096;
constexpr int IC = 8;
constexpr int C  = 10;
constexpr int O  = 16;

constexpr int RT = 16;           // r's per block (4 waves x 4 r-slots)
constexpr int BT = 8;            // b's per block
constexpr int NRBLK = R / RT;    // 256
constexpr int CO = C * O;        // 160

// Pass kernel: thread = (r, o). W[r,:,o,:] pinned in 80 VGPRs (loop-carried
// asm pin so the compiler cannot re-load it from memory). x staged in LDS
// (coalesced once, broadcast ds_reads in the loop). No in-loop barriers.
// Logits for iter k are uh . vsum (vsum = v0+..+v_{k-1}) — agreement is
// linear in v, so no b_ij buffer is needed.
template<int IT>
__global__ __launch_bounds__(256, 4)
void pass_kernel(const float* __restrict__ x, const float* __restrict__ W,
                 const float* __restrict__ vsum, float* __restrict__ s_part)
{
    const int tid  = threadIdx.x;
    const int w    = tid >> 6;
    const int lane = tid & 63;
    const int o    = lane & 15;      // capsule-vector element
    const int rs   = lane >> 4;      // r slot within wave
    const int lr   = w * 4 + rs;     // local r index (0..15)
    const int rblk = blockIdx.x;
    const int r    = rblk * RT + lr;
    const int b0   = blockIdx.y * BT;

    __shared__ float xL[BT * RT * IC];    // 4 KB: x slice for this block
    __shared__ float vL[BT][CO];          // 5 KB: vsum for this block's b's
    __shared__ float stage[4][BT][CO];    // 20 KB: per-wave partials

    // ---- coalesced cooperative load of x[b0..b0+7, rblk*16..+15, :] ----
    {
        const int bb = tid >> 5;          // 0..7
        const int f4 = tid & 31;          // float4 index within a b-row
        const float4 xv4 = *reinterpret_cast<const float4*>(
            x + ((size_t)(b0 + bb) * R + (size_t)rblk * RT) * IC + f4 * 4);
        *reinterpret_cast<float4*>(&xL[bb * RT * IC + f4 * 4]) = xv4;
    }
    if constexpr (IT >= 1) {
        for (int k = tid; k < BT * CO; k += 256)
            (&vL[0][0])[k] = vsum[(size_t)b0 * CO + k];
    }

    // ---- load W[r, c, o, 0..7] into registers (80 floats) ----
    float wreg[C][IC];
    {
        const float* wp = W + ((size_t)r * C * O + o) * IC;
        #pragma unroll
        for (int c = 0; c < C; ++c) {
            const float4* p = reinterpret_cast<const float4*>(wp + (size_t)c * O * IC);
            float4 w0 = p[0], w1 = p[1];
            wreg[c][0] = w0.x; wreg[c][1] = w0.y; wreg[c][2] = w0.z; wreg[c][3] = w0.w;
            wreg[c][4] = w1.x; wreg[c][5] = w1.y; wreg[c][6] = w1.z; wreg[c][7] = w1.w;
        }
    }

    __syncthreads();   // xL (and vL) ready

    for (int bb = 0; bb < BT; ++bb) {
        // Loop-carried pin: makes W-remat/reload from memory illegal, forcing
        // the 80 values to stay live in VGPRs across the whole loop.
        #pragma unroll
        for (int c = 0; c < C; ++c)
            #pragma unroll
            for (int i = 0; i < IC; ++i)
                asm volatile("" : "+v"(wreg[c][i]));

        // ---- x[b, r, 0..7] from LDS (broadcast across the 16 o-lanes) ----
        const float4 xa = *reinterpret_cast<const float4*>(&xL[bb * RT * IC + lr * IC]);
        const float4 xb = *reinterpret_cast<const float4*>(&xL[bb * RT * IC + lr * IC + 4]);
        const float xv[IC] = {xa.x, xa.y, xa.z, xa.w, xb.x, xb.y, xb.z, xb.w};

        // ---- u_hat[c] for this (r, o) ----
        float uh[C];
        #pragma unroll
        for (int c = 0; c < C; ++c) {
            float acc = 0.f;
            #pragma unroll
            for (int i = 0; i < IC; ++i) acc = fmaf(wreg[c][i], xv[i], acc);
            uh[c] = acc;
        }

        // ---- t[c] = routing_weight[c] * uh[c] ----
        float t[C];
        if constexpr (IT == 0) {
            #pragma unroll
            for (int c = 0; c < C; ++c) t[c] = 0.1f * uh[c];   // softmax of zeros
        } else {
            // logits = sum_o uh[c,o] * vsum[b,c,o]
            float a[C];
            #pragma unroll
            for (int c = 0; c < C; ++c) a[c] = uh[c] * vL[bb][c * O + o];
            #pragma unroll
            for (int m = 1; m < 16; m <<= 1) {
                #pragma unroll
                for (int c = 0; c < C; ++c) a[c] += __shfl_xor(a[c], m, 16);
            }
            // softmax over c, in-register (redundant across the 16 o-lanes)
            float mx = a[0];
            #pragma unroll
            for (int c = 1; c < C; ++c) mx = fmaxf(mx, a[c]);
            float sum = 0.f;
            #pragma unroll
            for (int c = 0; c < C; ++c) { a[c] = __expf(a[c] - mx); sum += a[c]; }
            float inv = 1.f / sum;
            #pragma unroll
            for (int c = 0; c < C; ++c) t[c] = (a[c] * inv) * uh[c];
        }

        // ---- reduce over the 4 r-slots in wave ----
        #pragma unroll
        for (int c = 0; c < C; ++c) {
            t[c] += __shfl_xor(t[c], 16, 64);
            t[c] += __shfl_xor(t[c], 32, 64);
        }

        // ---- stash per-wave partial (no barrier) ----
        if (rs == 0) {
            #pragma unroll
            for (int c = 0; c < C; ++c) stage[w][bb][c * O + o] = t[c];
        }
    }

    __syncthreads();

    // ---- epilogue: cross-wave sum, coalesced store ----
    if (tid < CO) {
        #pragma unroll 4
        for (int bb = 0; bb < BT; ++bb) {
            float s4 = stage[0][bb][tid] + stage[1][bb][tid]
                     + stage[2][bb][tid] + stage[3][bb][tid];
            s_part[((size_t)rblk * B + (b0 + bb)) * CO + tid] = s4;
        }
    }
}

// Sum partials over rblocks (4-way split), add bias, squash.
// Writes v (if v_out) and vsum_out = vin_sum + v (if vsum_out).
__global__ __launch_bounds__(640)
void reduce_squash(const float* __restrict__ s_part, const float* __restrict__ bias,
                   const float* __restrict__ vin_sum,
                   float* __restrict__ v_out, float* __restrict__ vsum_out)
{
    const int b = blockIdx.x;
    const int t = threadIdx.x;        // 640 threads: 4 quarters x 160
    __shared__ float part[4][CO];
    __shared__ float sv[CO];

    if (t < 4 * CO) {
        const int q  = t / CO;
        const int co = t % CO;
        float acc = 0.f;
        for (int blk = q * (NRBLK / 4); blk < (q + 1) * (NRBLK / 4); ++blk)
            acc += s_part[((size_t)blk * B + b) * CO + co];
        part[q][co] = acc;
    }
    __syncthreads();

    float s = 0.f;
    if (t < CO) {
        s = part[0][t] + part[1][t] + part[2][t] + part[3][t] + bias[t];
        sv[t] = s;
    }
    __syncthreads();

    if (t < CO) {
        const int c = t >> 4;
        float n = 0.f;
        #pragma unroll
        for (int oo = 0; oo < O; ++oo) { float z = sv[c * O + oo]; n += z * z; }
        float v = s * sqrtf(n) / (1.f + n);            // squash
        if (v_out)    v_out[(size_t)b * CO + t] = v;
        if (vsum_out) vsum_out[(size_t)b * CO + t] = (vin_sum ? vin_sum[(size_t)b * CO + t] : 0.f) + v;
    }
}

extern "C" void kernel_launch(void* const* d_in, const int* in_sizes, int n_in,
                              void* d_out, int out_size, void* d_ws, size_t ws_size,
                              hipStream_t stream)
{
    const float* x    = (const float*)d_in[0];
    const float* W    = (const float*)d_in[1];
    const float* bias = (const float*)d_in[2];
    float* out = (float*)d_out;

    float* ws     = (float*)d_ws;
    float* s_part = ws;                                    // NRBLK*B*CO floats (21 MB)
    float* vsumA  = s_part + (size_t)NRBLK * B * CO;       // B*CO floats
    float* vsumB  = vsumA + (size_t)B * CO;                // B*CO floats

    dim3 grid(NRBLK, B / BT);
    dim3 blk(256);

    // iter 0: c = 1/10 uniform
    pass_kernel<0><<<grid, blk, 0, stream>>>(x, W, nullptr, s_part);
    reduce_squash<<<B, 640, 0, stream>>>(s_part, bias, nullptr, nullptr, vsumA);   // vsumA = v0
    // iter 1: logits = uh . v0
    pass_kernel<1><<<grid, blk, 0, stream>>>(x, W, vsumA, s_part);
    reduce_squash<<<B, 640, 0, stream>>>(s_part, bias, vsumA, nullptr, vsumB);     // vsumB = v0+v1
    // iter 2: logits = uh . (v0+v1)
    pass_kernel<2><<<grid, blk, 0, stream>>>(x, W, vsumB, s_part);
    reduce_squash<<<B, 640, 0, stream>>>(s_part, bias, nullptr, out, nullptr);     // out = v2
}